// Round 13
// baseline (206.784 us; speedup 1.0000x reference)
//
#include <hip/hip_runtime.h>

typedef float  f4    __attribute__((ext_vector_type(4)));
typedef float  f32x4 __attribute__((ext_vector_type(4)));
typedef short  s16x8 __attribute__((ext_vector_type(8)));
typedef unsigned int u32x4 __attribute__((ext_vector_type(4)));

#define L_SEQ 2048
#define D4    16
#define NC4   512
#define RAD   128
#define NBH   48

// Split architecture (R11-proven best): band kernel first (reads K/Q, writes
// the 68-chunk window per 16-row tile), then the pure-write zero streamer
// (exact complement). Coverage contract HW-validated since R10.
// R13 change: B uses SWAPPED MFMA operands -- mfma(A=K,B=Q) -- so D's reg
// axis walks j: each lane stores one f4 (4 consecutive j) per col-tile
// instead of 4 scalar stores. Q fragments prefetch before K staging.

__device__ __forceinline__ unsigned bf16rne(float f) {
    unsigned u = __float_as_uint(f);
    return (u + 0x7FFFu + ((u >> 16) & 1u)) >> 16;   // round-to-nearest-even
}

// ---------------- Kernel B: MFMA band compute, swapped operands ----------------
#define TI    64             // rows per block (4 waves x 16-row MFMA tiles)
#define NTIL  (L_SEQ / TI)   // 32
#define BBLK  (NBH * NTIL)   // 1536
#define KROWS (TI + 2*RAD)   // 320 staged K rows

__global__ __launch_bounds__(256, 4)
void band_mfma(const float* __restrict__ Qg, const float* __restrict__ Kg,
               float* __restrict__ outg)
{
    // K rows as 8 16B-units (8 bf16, d-ascending); slot = si*8 + (u ^ (si&7))
    __shared__ u32x4 sK[KROWS * 8];     // 40960 B -> 4 blocks/CU

    const int t  = threadIdx.x;
    const int id = blockIdx.x;
    // bijective XCD swizzle (BBLK % 8 == 0)
    const int swz = (id & 7) * (BBLK / 8) + (id >> 3);
    const int bh  = swz >> 5;
    const int i0  = (swz & (NTIL - 1)) * TI;

    const f4* __restrict__ K4 = reinterpret_cast<const f4*>(Kg) + (size_t)bh * L_SEQ * D4;
    const f4* __restrict__ Q4 = reinterpret_cast<const f4*>(Qg) + (size_t)bh * L_SEQ * D4;
    f4* __restrict__ O4       = reinterpret_cast<f4*>(outg)     + (size_t)bh * L_SEQ * NC4;

    const int kbase = i0 - RAD;
    const int wv = t >> 6, l = t & 63;
    const int ib = i0 + 16 * wv;
    const int m  = l & 15, g = l >> 4;

    // ---- Q B-fragments: issue these global loads BEFORE K staging so their
    // latency hides under the 20 staging loads. B-frag: col = lane&15 -> Q row
    // ib+m; k-elements use the same (g,e)->d map as the K A-frags.
    const size_t qb = (size_t)(ib + m) * D4;
    const f4 qa = Q4[qb + 2 * g];
    const f4 qv = Q4[qb + 2 * g + 1];
    const f4 qc = Q4[qb + 8 + 2 * g];
    const f4 qd = Q4[qb + 8 + 2 * g + 1];

    // ---- stage K as bf16: 2560 units, 10 per thread
#pragma unroll 2
    for (int itr = 0; itr < 10; ++itr) {
        const int s  = itr * 256 + t;
        const int si = s >> 3, u = s & 7;
        int row = kbase + si;
        row = row < 0 ? 0 : (row > L_SEQ - 1 ? L_SEQ - 1 : row);  // clamp; never read
        const f4 a = K4[(size_t)row * D4 + 2 * u];
        const f4 b = K4[(size_t)row * D4 + 2 * u + 1];
        u32x4 w;
        w.x = bf16rne(a.x) | (bf16rne(a.y) << 16);
        w.y = bf16rne(a.z) | (bf16rne(a.w) << 16);
        w.z = bf16rne(b.x) | (bf16rne(b.y) << 16);
        w.w = bf16rne(b.z) | (bf16rne(b.w) << 16);
        sK[si * 8 + (u ^ (si & 7))] = w;
    }

    // pack Q fragments while stores drain
    s16x8 BQ1, BQ2;
    {
        u32x4 wa, wb;
        wa.x = bf16rne(qa.x) | (bf16rne(qa.y) << 16);
        wa.y = bf16rne(qa.z) | (bf16rne(qa.w) << 16);
        wa.z = bf16rne(qv.x) | (bf16rne(qv.y) << 16);
        wa.w = bf16rne(qv.z) | (bf16rne(qv.w) << 16);
        wb.x = bf16rne(qc.x) | (bf16rne(qc.y) << 16);
        wb.y = bf16rne(qc.z) | (bf16rne(qc.w) << 16);
        wb.z = bf16rne(qd.x) | (bf16rne(qd.y) << 16);
        wb.w = bf16rne(qd.z) | (bf16rne(qd.w) << 16);
        BQ1 = __builtin_bit_cast(s16x8, wa);
        BQ2 = __builtin_bit_cast(s16x8, wb);
    }
    __syncthreads();

    // ---- MFMA: wave wv owns rows [ib, ib+16); col-tiles c over the window.
    // Swapped operands: A = K tile (D row -> j), B = Q tile (D col -> i=ib+m).
    {
        const int c_lo  = (ib < RAD) ? ((RAD - ib) >> 4) : 0;       // skip j<0 tiles
        const int c_hi0 = (2176 - ib) >> 4;                         // skip j>=2048 tiles
        const int c_hi  = c_hi0 < 17 ? c_hi0 : 17;
        const int i     = ib + m;
        for (int c = c_lo; c < c_hi; ++c) {
            const int si = 16 * (wv + c) + m;                       // A row = lane&15
            const u32x4 a1 = sK[si * 8 + ((g    ) ^ (si & 7))];
            const u32x4 a2 = sK[si * 8 + ((4 + g) ^ (si & 7))];
            f32x4 acc = {0.f, 0.f, 0.f, 0.f};
            acc = __builtin_amdgcn_mfma_f32_16x16x32_bf16(__builtin_bit_cast(s16x8, a1), BQ1, acc, 0, 0, 0);
            acc = __builtin_amdgcn_mfma_f32_16x16x32_bf16(__builtin_bit_cast(s16x8, a2), BQ2, acc, 0, 0, 0);
            const int j0 = ib - RAD + 16 * c + 4 * g;               // D row = 4g+r -> j
            f4 v;
            v.x = ((unsigned)(i - (j0 + 0) + RAD) <= 2u * RAD) ? acc[0] : 0.f;
            v.y = ((unsigned)(i - (j0 + 1) + RAD) <= 2u * RAD) ? acc[1] : 0.f;
            v.z = ((unsigned)(i - (j0 + 2) + RAD) <= 2u * RAD) ? acc[2] : 0.f;
            v.w = ((unsigned)(i - (j0 + 3) + RAD) <= 2u * RAD) ? acc[3] : 0.f;
            O4[(size_t)i * NC4 + (j0 >> 2)] = v;
        }
    }
}

// ---------------- Kernel Z: pure streaming zero-fill of the complement ----------------
#define ZROWS 16
#define ZBLK  (NBH * (L_SEQ / ZROWS))   // 6144

__global__ __launch_bounds__(256)
void zero_oob(float* __restrict__ outg)
{
    const int t  = threadIdx.x;
    const int id = blockIdx.x;
    const int bh = id >> 7;
    const int r0 = (id & 127) * ZROWS;          // 16-aligned row-tile base
    f4* __restrict__ O4 = reinterpret_cast<f4*>(outg) + (size_t)bh * L_SEQ * NC4;

    const int wlo = (r0 > RAD ? r0 - RAD : 0) >> 2;
    const int whe = r0 + 144;
    const int whi = (whe < L_SEQ ? whe : L_SEQ) >> 2;
    const int wid = whi - wlo;                  // 36..68
    const int nz  = NC4 - wid;                  // 444..476 zero chunks per row

    const int  jA  = t < wlo ? t : t + wid;     // t < nz always
    const int  z2  = t + 256;
    const int  jB  = z2 < wlo ? z2 : z2 + wid;
    const bool doB = z2 < nz;
    const f4 zero4 = {0.f, 0.f, 0.f, 0.f};

#pragma unroll
    for (int r = 0; r < ZROWS; ++r) {
        f4* rowp = O4 + (size_t)(r0 + r) * NC4;
        rowp[jA] = zero4;
        if (doB) rowp[jB] = zero4;
    }
}

extern "C" void kernel_launch(void* const* d_in, const int* in_sizes, int n_in,
                              void* d_out, int out_size, void* d_ws, size_t ws_size,
                              hipStream_t stream) {
    const float* Q = (const float*)d_in[0];
    const float* K = (const float*)d_in[1];
    float* out = (float*)d_out;
    band_mfma<<<BBLK, 256, 0, stream>>>(Q, K, out);
    zero_oob<<<ZBLK, 256, 0, stream>>>(out);
}